// Round 16
// baseline (146.781 us; speedup 1.0000x reference)
//
#include <hip/hip_runtime.h>
#include <hip/hip_bf16.h>

typedef __attribute__((ext_vector_type(8))) short short8;
typedef __attribute__((ext_vector_type(4))) float floatx4;
typedef __attribute__((ext_vector_type(4))) unsigned int u32x4;

static constexpr int Hn = 16, DHn = 64, Cn = 1024;
static constexpr int Bn = 4, Tn = 2048;
static constexpr int Mtot = Bn * Tn;               // 8192
static constexpr size_t QKV_STRIDE = (size_t)Bn * Hn * Tn * DHn;  // 8388608 elems

__device__ __forceinline__ unsigned short bfbits(float f) {
    __hip_bfloat16 h = __float2bfloat16(f);
    return __builtin_bit_cast(unsigned short, h);
}

__device__ __forceinline__ unsigned int cvtpk(float a, float b) {
    unsigned int r;
    asm("v_cvt_pk_bf16_f32 %0, %1, %2" : "=v"(r) : "v"(a), "v"(b));
    return r;
}

__device__ __forceinline__ void gl_lds16(const void* g, void* lds_base) {
    __builtin_amdgcn_global_load_lds(
        (const __attribute__((address_space(1))) unsigned int*)g,
        (__attribute__((address_space(3))) unsigned int*)lds_base, 16, 0, 0);
}

// ---------------- f32 -> bf16 convert (vectorized x4) ----------------
__global__ void conv_kernel(const float4* __restrict__ src, ushort4* __restrict__ dst, int n4) {
    int i = blockIdx.x * blockDim.x + threadIdx.x;
    if (i < n4) {
        float4 v = src[i];
        ushort4 o;
        o.x = bfbits(v.x); o.y = bfbits(v.y); o.z = bfbits(v.z); o.w = bfbits(v.w);
        dst[i] = o;
    }
}

// ---------------- fused Wq/Wk/Wv transpose+convert: z = w*16 + head ----------------
__global__ void tconv3_kernel(const float* __restrict__ Wq, const float* __restrict__ Wk,
                              const float* __restrict__ Wv, __hip_bfloat16* __restrict__ wT) {
    __shared__ float tile[32][33];
    const int z = blockIdx.z, w = z >> 4, hh = z & 15;
    const float* s = (w == 0 ? Wq : (w == 1 ? Wk : Wv)) + (size_t)hh * Cn * DHn;
    __hip_bfloat16* d = wT + (size_t)z * Cn * DHn;
    const float scale = (w == 0) ? 0.125f * 1.44269504088896f : 1.0f;
    int c0 = blockIdx.x * 32;
    int r0 = blockIdx.y * 32;
    int tx = threadIdx.x, ty = threadIdx.y;
    for (int i = 0; i < 4; ++i) {
        int r = r0 + ty + i * 8;
        tile[ty + i * 8][tx] = s[(size_t)r * DHn + c0 + tx];
    }
    __syncthreads();
    for (int i = 0; i < 4; ++i) {
        int c = c0 + ty + i * 8;
        d[(size_t)c * Cn + r0 + tx] = __float2bfloat16(tile[tx][ty + i * 8] * scale);
    }
}

// ---------------- transpose + convert: src [R][C] f32 -> dst [C][R] bf16 (Wo) ----------------
__global__ void tconv_kernel(const float* __restrict__ src, __hip_bfloat16* __restrict__ dst,
                             int R, int C) {
    __shared__ float tile[32][33];
    int c0 = blockIdx.x * 32;
    int r0 = blockIdx.y * 32;
    int tx = threadIdx.x, ty = threadIdx.y;
    for (int i = 0; i < 4; ++i) {
        int r = r0 + ty + i * 8;
        tile[ty + i * 8][tx] = src[(size_t)r * C + c0 + tx];
    }
    __syncthreads();
    for (int i = 0; i < 4; ++i) {
        int c = c0 + ty + i * 8;
        dst[(size_t)c * R + r0 + tx] = __float2bfloat16(tile[tx][ty + i * 8]);
    }
}

// ---------------- GEMM v6: BK=64 dbuf + COUNTED vmcnt(8) (no in-loop drain) ----------------
// Per step: [vmcnt(8): tile t landed][barrier][ds_read ALL frags -> regs]
// [lgkmcnt(0)][barrier: everyone done reading][STAGE t+2 into buf t&1][32 MFMA].
// Loads get ~2 compute phases to land. Tail: clamped STAGE keeps vmcnt uniform,
// dummy writes go to the dead buffer (t=14) or after all reads (t=15) -- safe.
// MODE 0: scatter q/k [B,H,T,DH]; v transposed [B,H,DH,T] with permuted columns.
// MODE 1: +bias, f32 out.
template<int MODE>
__global__ __launch_bounds__(256) void gemm_kernel(
    const __hip_bfloat16* __restrict__ A,   // [M][1024]
    const __hip_bfloat16* __restrict__ BT,  // [N][1024]
    const float* __restrict__ bias,
    __hip_bfloat16* __restrict__ out_qkv,   // q base; k,v at +QKV_STRIDE
    float* __restrict__ out_f32)
{
    constexpr int K = Cn;
    constexpr int NSTEP = K / 64;             // 16
    __shared__ char smem[65536];               // [buf][A 16KB | B 16KB]

    const int m0 = blockIdx.x * 128;
    const int n0 = blockIdx.y * 128;

    const int tid = threadIdx.x;
    const int lane = tid & 63, wid = tid >> 6;
    const int wy = wid >> 1, wx = wid & 1;
    const int fr = lane & 15, g = lane >> 4;
    const int rxor = (fr & 7) << 4;

    floatx4 acc[4][4] = {};

    int srow[4], scol[4], doff[4];
#pragma unroll
    for (int i = 0; i < 4; ++i) {
        int byteoff = wid * 4096 + i * 1024 + lane * 16;
        int r = byteoff >> 7;
        int ch = (byteoff >> 4) & 7;
        srow[i] = r;
        scol[i] = (ch ^ (r & 7)) << 3;
        doff[i] = wid * 4096 + i * 1024;       // wave-uniform LDS offset
    }

#define STAGE_T(tile, buf)                                                              \
    {                                                                                   \
        const int k0s = (tile) * 64;                                                    \
        char* dstb = smem + (buf) * 32768;                                              \
        _Pragma("unroll")                                                               \
        for (int i = 0; i < 4; ++i) {                                                   \
            gl_lds16(&A[(size_t)(m0 + srow[i]) * K + k0s + scol[i]], dstb + doff[i]);   \
            gl_lds16(&BT[(size_t)(n0 + srow[i]) * K + k0s + scol[i]], dstb + 16384 + doff[i]); \
        }                                                                               \
    }

    // prologue: tiles 0,1 in flight (16 loads outstanding)
    STAGE_T(0, 0);
    STAGE_T(1, 1);

    for (int t = 0; t < NSTEP; ++t) {
        // tile t's 8 loads are the oldest beyond the newest 8 -> landed
        asm volatile("s_waitcnt vmcnt(8)" ::: "memory");
        __builtin_amdgcn_s_barrier();

        const char* lA0 = smem + (t & 1) * 32768;
        const char* lB0 = lA0 + 16384;
        short8 af[2][4], bf[2][4];
#pragma unroll
        for (int kk = 0; kk < 2; ++kk)
#pragma unroll
            for (int t4 = 0; t4 < 4; ++t4) {
                af[kk][t4] = *(const short8*)(lA0 + (wy * 64 + t4 * 16 + fr) * 128 + ((kk * 64 + g * 16) ^ rxor));
                bf[kk][t4] = *(const short8*)(lB0 + (wx * 64 + t4 * 16 + fr) * 128 + ((kk * 64 + g * 16) ^ rxor));
            }
        // all frag reads complete before anyone overwrites this buffer
        asm volatile("s_waitcnt lgkmcnt(0)" ::: "memory");
        __builtin_amdgcn_s_barrier();

        // stage t+2 into buf t&1 (clamped at tail: keeps vmcnt uniform; dummy
        // writes land in a buffer that is never read again)
        int nt = t + 2; if (nt > NSTEP - 1) nt = NSTEP - 1;
        STAGE_T(nt, t & 1);

        __builtin_amdgcn_s_setprio(1);
#pragma unroll
        for (int kk = 0; kk < 2; ++kk)
#pragma unroll
            for (int tm = 0; tm < 4; ++tm)
#pragma unroll
                for (int tn = 0; tn < 4; ++tn)
                    acc[tm][tn] = __builtin_amdgcn_mfma_f32_16x16x32_bf16(af[kk][tm], bf[kk][tn], acc[tm][tn], 0, 0, 0);
        __builtin_amdgcn_s_setprio(0);
    }
#undef STAGE_T

    for (int tm = 0; tm < 4; ++tm) {
        int rbase = m0 + wy * 64 + tm * 16 + g * 4;
        for (int tn = 0; tn < 4; ++tn) {
            int nc = n0 + wx * 64 + tn * 16 + fr;
            if (MODE == 0) {
                int w = nc >> 10, rem = nc & 1023, hh = rem >> 6, dd = rem & 63;
                if (w == 2) {
                    int b = rbase >> 11, t0 = rbase & 2047;
                    // permuted column position within the 32-block (quad-aligned t0)
                    int pos = (t0 & ~31) | (((t0 >> 2) & 3) << 3) | (((t0 >> 4) & 1) << 2);
                    ushort4 pk;
                    pk.x = bfbits(acc[tm][tn][0]);
                    pk.y = bfbits(acc[tm][tn][1]);
                    pk.z = bfbits(acc[tm][tn][2]);
                    pk.w = bfbits(acc[tm][tn][3]);
                    *(ushort4*)(&out_qkv[2 * QKV_STRIDE +
                        ((size_t)((b * Hn + hh) * DHn + dd)) * Tn + pos]) = pk;
                } else {
                    for (int r = 0; r < 4; ++r) {
                        int m = rbase + r;
                        int b = m >> 11, t = m & 2047;
                        out_qkv[(size_t)w * QKV_STRIDE + (((size_t)(b * Hn + hh) * Tn + t) << 6) + dd] =
                            __float2bfloat16(acc[tm][tn][r]);
                    }
                }
            } else {
                float bs = bias[nc];
                for (int r = 0; r < 4; ++r) {
                    int m = rbase + r;
                    out_f32[(size_t)m * Cn + nc] = acc[tm][tn][r] + bs;
                }
            }
        }
    }
}

// ---------------- causal flash attention v12 (unchanged from R15) ----------------
__global__ __launch_bounds__(256, 4) void attn_kernel(
    const __hip_bfloat16* __restrict__ q,
    const __hip_bfloat16* __restrict__ k,
    const __hip_bfloat16* __restrict__ vt,
    __hip_bfloat16* __restrict__ ao)
{
    __shared__ char smem[32768];   // K bufs [2][8KB] @0, V bufs [2][8KB] @16384

    const int id = blockIdx.x;               // 0..1023
    const int xcd = id & 7;
    const int rnk = id >> 3;                 // 0..127 within XCD stream
    const int tile = 15 - (rnk >> 3);        // longest-first (LPT)
    const int bh = xcd * 8 + (rnk & 7);      // XCD-clustered heads
    const int b = bh >> 4, h = bh & 15;
    const int tid = threadIdx.x, lane = tid & 63, wid = tid >> 6;
    const int fr = lane & 15, g = lane >> 4;
    const size_t base = (size_t)bh * Tn * DHn;
    const int rxor = (fr & 7) << 4;

    const int r0 = wid * 16 + (lane >> 3);
    const int c8 = ((lane & 7) ^ (r0 & 7)) * 8;
    const int ldk0 = wid * 2048;

    short8 ones;
#pragma unroll
    for (int z = 0; z < 8; ++z) ones[z] = (short)0x3F80;

    const int qb0 = tile * 128;
    const int q0 = qb0 + wid * 32;
    const int nkv = qb0 / 64 + 2;

    short8 aq[2][2];
#pragma unroll
    for (int rq = 0; rq < 2; ++rq)
#pragma unroll
        for (int kk = 0; kk < 2; ++kk)
            aq[rq][kk] = *(const short8*)(&q[base + (size_t)(q0 + rq * 16 + fr) * DHn + kk * 32 + g * 8]);

    floatx4 o[2][4] = {};
    floatx4 o5[2] = {};    // l-sum accumulators (ones-MFMA)

    // prologue: stage j=0 -> buf0
    {
        char* kd = smem + ldk0;
        char* vd = smem + 16384 + ldk0;
        gl_lds16(&k[base + (size_t)r0 * DHn + c8], kd);
        gl_lds16(&k[base + (size_t)(r0 + 8) * DHn + c8], kd + 1024);
        gl_lds16(&vt[base + (size_t)r0 * Tn + c8], vd);
        gl_lds16(&vt[base + (size_t)(r0 + 8) * Tn + c8], vd + 1024);
    }
    asm volatile("s_waitcnt vmcnt(0)" ::: "memory");
    __builtin_amdgcn_s_barrier();

    int cur = 0;
    for (int j = 0; j < nkv; ++j) {
        const int kv0 = j * 64;

        // issue j+1 -> buf cur^1 (closed by the previous step's barrier)
        {
            const int nv0 = kv0 + 64;
            char* kd = smem + (cur ^ 1) * 8192 + ldk0;
            char* vd = smem + 16384 + (cur ^ 1) * 8192 + ldk0;
            gl_lds16(&k[base + (size_t)(nv0 + r0) * DHn + c8], kd);
            gl_lds16(&k[base + (size_t)(nv0 + r0 + 8) * DHn + c8], kd + 1024);
            gl_lds16(&vt[base + (size_t)r0 * Tn + nv0 + c8], vd);
            gl_lds16(&vt[base + (size_t)(r0 + 8) * Tn + nv0 + c8], vd + 1024);
        }

        if (kv0 < q0 + 32) {
            const char* lkc = smem + cur * 8192;
            const char* lvc = smem + 16384 + cur * 8192;

            // ---- QK^T (swapped): s[rq][cg] row k = cg*16+g*4+r, col q = fr ----
            floatx4 s[2][4] = {};
            __builtin_amdgcn_s_setprio(1);
#pragma unroll
            for (int kk = 0; kk < 2; ++kk)
#pragma unroll
                for (int cg = 0; cg < 4; ++cg) {
                    short8 kf = *(const short8*)(lkc + (cg * 16 + fr) * 128 + ((g * 16 + kk * 64) ^ rxor));
                    s[0][cg] = __builtin_amdgcn_mfma_f32_16x16x32_bf16(kf, aq[0][kk], s[0][cg], 0, 0, 0);
                    s[1][cg] = __builtin_amdgcn_mfma_f32_16x16x32_bf16(kf, aq[1][kk], s[1][cg], 0, 0, 0);
                }
            __builtin_amdgcn_s_setprio(0);

            // ---- causal mask (diagonal region only) ----
            if (kv0 + 64 > q0) {
#pragma unroll
                for (int rq = 0; rq < 2; ++rq) {
                    int qg = q0 + rq * 16 + fr;
#pragma unroll
                    for (int cg = 0; cg < 4; ++cg) {
                        int kg = kv0 + cg * 16 + g * 4;
#pragma unroll
                        for (int r = 0; r < 4; ++r)
                            if (kg + r > qg) s[rq][cg][r] = -1e30f;
                    }
                }
            }

            // ---- fixed-reference softmax: p = exp2(s); pack via v_cvt_pk_bf16_f32 ----
            short8 pb[2][2];
#pragma unroll
            for (int rq = 0; rq < 2; ++rq) {
#pragma unroll
                for (int cg = 0; cg < 4; ++cg)
#pragma unroll
                    for (int r = 0; r < 4; ++r)
                        s[rq][cg][r] = __builtin_amdgcn_exp2f(s[rq][cg][r]);
#pragma unroll
                for (int kt = 0; kt < 2; ++kt) {
                    u32x4 wv;
                    wv[0] = cvtpk(s[rq][2 * kt][0],     s[rq][2 * kt][1]);
                    wv[1] = cvtpk(s[rq][2 * kt][2],     s[rq][2 * kt][3]);
                    wv[2] = cvtpk(s[rq][2 * kt + 1][0], s[rq][2 * kt + 1][1]);
                    wv[3] = cvtpk(s[rq][2 * kt + 1][2], s[rq][2 * kt + 1][3]);
                    pb[rq][kt] = __builtin_bit_cast(short8, wv);
                }
            }

            // ---- l via ones-MFMA + PV (contiguous b128 reads: V^T columns pre-permuted) ----
            __builtin_amdgcn_s_setprio(1);
#pragma unroll
            for (int rq = 0; rq < 2; ++rq)
#pragma unroll
                for (int kt = 0; kt < 2; ++kt)
                    o5[rq] = __builtin_amdgcn_mfma_f32_16x16x32_bf16(ones, pb[rq][kt], o5[rq], 0, 0, 0);
#pragma unroll
            for (int kt = 0; kt < 2; ++kt)
#pragma unroll
                for (int dg = 0; dg < 4; ++dg) {
                    const int vrow = (dg * 16 + fr) * 128;
                    short8 vf = *(const short8*)(lvc + vrow + ((kt * 64 + g * 16) ^ rxor));
                    o[0][dg] = __builtin_amdgcn_mfma_f32_16x16x32_bf16(vf, pb[0][kt], o[0][dg], 0, 0, 0);
                    o[1][dg] = __builtin_amdgcn_mfma_f32_16x16x32_bf16(vf, pb[1][kt], o[1][dg], 0, 0, 0);
                }
            __builtin_amdgcn_s_setprio(0);
        }

        asm volatile("s_waitcnt vmcnt(0)" ::: "memory");
        __builtin_amdgcn_s_barrier();
        cur ^= 1;
    }

    // ---- epilogue: normalize (l = o5 via MFMA rowsum), transpose, store ----
    char* myscr = smem + wid * 4096;   // per-wave 16x64 f32 region
    const int rr = lane >> 2, cc = lane & 3;
#pragma unroll
    for (int rq = 0; rq < 2; ++rq) {
        const float inv = 1.0f / o5[rq][0];
#pragma unroll
        for (int dg = 0; dg < 4; ++dg) {
            floatx4 wv = o[rq][dg] * inv;
            *(floatx4*)(myscr + fr * 256 + ((dg * 64 + g * 16) ^ rxor)) = wv;
        }
        asm volatile("s_waitcnt lgkmcnt(0)" ::: "memory");
        float4 f0 = *(const float4*)(myscr + rr * 256 + ((cc * 64 + 0) ^ ((rr & 7) << 4)));
        float4 f1 = *(const float4*)(myscr + rr * 256 + ((cc * 64 + 16) ^ ((rr & 7) << 4)));
        float4 f2 = *(const float4*)(myscr + rr * 256 + ((cc * 64 + 32) ^ ((rr & 7) << 4)));
        float4 f3 = *(const float4*)(myscr + rr * 256 + ((cc * 64 + 48) ^ ((rr & 7) << 4)));
        short8 pk0, pk1;
        pk0[0] = (short)bfbits(f0.x); pk0[1] = (short)bfbits(f0.y);
        pk0[2] = (short)bfbits(f0.z); pk0[3] = (short)bfbits(f0.w);
        pk0[4] = (short)bfbits(f1.x); pk0[5] = (short)bfbits(f1.y);
        pk0[6] = (short)bfbits(f1.z); pk0[7] = (short)bfbits(f1.w);
        pk1[0] = (short)bfbits(f2.x); pk1[1] = (short)bfbits(f2.y);
        pk1[2] = (short)bfbits(f2.z); pk1[3] = (short)bfbits(f2.w);
        pk1[4] = (short)bfbits(f3.x); pk1[5] = (short)bfbits(f3.y);
        pk1[6] = (short)bfbits(f3.z); pk1[7] = (short)bfbits(f3.w);
        size_t orow = ((size_t)(b * Tn + q0 + rq * 16 + rr)) * Cn + h * 64 + cc * 16;
        *(short8*)(&ao[orow]) = pk0;
        *(short8*)(&ao[orow + 8]) = pk1;
        asm volatile("s_waitcnt lgkmcnt(0)" ::: "memory");
    }
}

extern "C" void kernel_launch(void* const* d_in, const int* in_sizes, int n_in,
                              void* d_out, int out_size, void* d_ws, size_t ws_size,
                              hipStream_t stream) {
    const float* x  = (const float*)d_in[0];
    const float* Wq = (const float*)d_in[1];
    const float* Wk = (const float*)d_in[2];
    const float* Wv = (const float*)d_in[3];
    const float* Wo = (const float*)d_in[4];
    const float* bo = (const float*)d_in[5];
    float* out = (float*)d_out;

    char* ws = (char*)d_ws;
    __hip_bfloat16* xb  = (__hip_bfloat16*)(ws);                    // [8192][1024]        16 MB
    __hip_bfloat16* wT  = (__hip_bfloat16*)(ws + 16777216);         // [3][1024][1024]      6 MB
    __hip_bfloat16* woT = (__hip_bfloat16*)(ws + 23068672);         // [1024][1024]         2 MB
    __hip_bfloat16* qb  = (__hip_bfloat16*)(ws + 25165824);         // q,k,v each 16 MB
    __hip_bfloat16* ao  = (__hip_bfloat16*)(ws + 75497472);         // [8192][1024]        16 MB

    // x -> bf16
    conv_kernel<<<(Mtot * Cn / 4 + 255) / 256, 256, 0, stream>>>(
        (const float4*)x, (ushort4*)xb, Mtot * Cn / 4);
    // fused Wq/Wk/Wv transpose+convert (Wq carries 0.125*log2e)
    tconv3_kernel<<<dim3(2, 32, 48), dim3(32, 8), 0, stream>>>(Wq, Wk, Wv, wT);
    // Wo transpose+convert
    tconv_kernel<<<dim3(32, 32, 1), dim3(32, 8), 0, stream>>>(Wo, woT, Cn, Cn);

    // QKV projection: M=8192, N=3072 (V stored transposed, columns permuted)
    gemm_kernel<0><<<dim3(Mtot / 128, 3072 / 128), 256, 0, stream>>>(
        xb, wT, nullptr, qb, nullptr);

    // causal flash attention: 1024 single-tile blocks, LPT per XCD, 4 blocks/CU
    attn_kernel<<<dim3(1024), 256, 0, stream>>>(
        qb, qb + QKV_STRIDE, qb + 2 * QKV_STRIDE, ao);

    // output projection: M=8192, N=1024, +bias, f32 out
    gemm_kernel<1><<<dim3(Mtot / 128, Cn / 128), 256, 0, stream>>>(
        ao, woT, bo, nullptr, out);
}

// Round 17
// 138.022 us; speedup vs baseline: 1.0635x; 1.0635x over previous
//
#include <hip/hip_runtime.h>
#include <hip/hip_bf16.h>

typedef __attribute__((ext_vector_type(8))) short short8;
typedef __attribute__((ext_vector_type(4))) float floatx4;
typedef __attribute__((ext_vector_type(4))) unsigned int u32x4;

static constexpr int Hn = 16, DHn = 64, Cn = 1024;
static constexpr int Bn = 4, Tn = 2048;
static constexpr int Mtot = Bn * Tn;               // 8192
static constexpr size_t QKV_STRIDE = (size_t)Bn * Hn * Tn * DHn;  // 8388608 elems

__device__ __forceinline__ unsigned short bfbits(float f) {
    __hip_bfloat16 h = __float2bfloat16(f);
    return __builtin_bit_cast(unsigned short, h);
}

__device__ __forceinline__ unsigned int cvtpk(float a, float b) {
    unsigned int r;
    asm("v_cvt_pk_bf16_f32 %0, %1, %2" : "=v"(r) : "v"(a), "v"(b));
    return r;
}

__device__ __forceinline__ void gl_lds16(const void* g, void* lds_base) {
    __builtin_amdgcn_global_load_lds(
        (const __attribute__((address_space(1))) unsigned int*)g,
        (__attribute__((address_space(3))) unsigned int*)lds_base, 16, 0, 0);
}

// ---------------- f32 -> bf16 convert (8 floats/thread, single 16B store) ----------------
__global__ void conv_kernel(const float4* __restrict__ src, ushort4* __restrict__ dst, int n8) {
    int i = blockIdx.x * blockDim.x + threadIdx.x;
    if (i < n8) {
        float4 a = src[2 * i], b = src[2 * i + 1];
        u32x4 o;
        o[0] = cvtpk(a.x, a.y);
        o[1] = cvtpk(a.z, a.w);
        o[2] = cvtpk(b.x, b.y);
        o[3] = cvtpk(b.z, b.w);
        *(u32x4*)(&dst[2 * i]) = o;
    }
}

// ---------------- fused Wq/Wk/Wv transpose+convert: z = w*16 + head ----------------
__global__ void tconv3_kernel(const float* __restrict__ Wq, const float* __restrict__ Wk,
                              const float* __restrict__ Wv, __hip_bfloat16* __restrict__ wT) {
    __shared__ float tile[32][33];
    const int z = blockIdx.z, w = z >> 4, hh = z & 15;
    const float* s = (w == 0 ? Wq : (w == 1 ? Wk : Wv)) + (size_t)hh * Cn * DHn;
    __hip_bfloat16* d = wT + (size_t)z * Cn * DHn;
    const float scale = (w == 0) ? 0.125f * 1.44269504088896f : 1.0f;
    int c0 = blockIdx.x * 32;
    int r0 = blockIdx.y * 32;
    int tx = threadIdx.x, ty = threadIdx.y;
    for (int i = 0; i < 4; ++i) {
        int r = r0 + ty + i * 8;
        tile[ty + i * 8][tx] = s[(size_t)r * DHn + c0 + tx];
    }
    __syncthreads();
    for (int i = 0; i < 4; ++i) {
        int c = c0 + ty + i * 8;
        d[(size_t)c * Cn + r0 + tx] = __float2bfloat16(tile[tx][ty + i * 8] * scale);
    }
}

// ---------------- transpose + convert: src [R][C] f32 -> dst [C][R] bf16 (Wo) ----------------
__global__ void tconv_kernel(const float* __restrict__ src, __hip_bfloat16* __restrict__ dst,
                             int R, int C) {
    __shared__ float tile[32][33];
    int c0 = blockIdx.x * 32;
    int r0 = blockIdx.y * 32;
    int tx = threadIdx.x, ty = threadIdx.y;
    for (int i = 0; i < 4; ++i) {
        int r = r0 + ty + i * 8;
        tile[ty + i * 8][tx] = src[(size_t)r * C + c0 + tx];
    }
    __syncthreads();
    for (int i = 0; i < 4; ++i) {
        int c = c0 + ty + i * 8;
        dst[(size_t)c * R + r0 + tx] = __float2bfloat16(tile[tx][ty + i * 8]);
    }
}

// ---------------- GEMM: 128x128, BK=64, 2-phase dbuf DMA (R15-proven, 851 TF) ----------------
// MODE 0: scatter q/k [B,H,T,DH]; v transposed [B,H,DH,T] with PERMUTED columns
// (pos = 8*g' + 4*hi + j within each 32-block) so attn PV reads are contiguous b128.
// MODE 1: +bias, f32 out.
template<int MODE>
__global__ __launch_bounds__(256) void gemm_kernel(
    const __hip_bfloat16* __restrict__ A,   // [M][1024]
    const __hip_bfloat16* __restrict__ BT,  // [N][1024]
    const float* __restrict__ bias,
    __hip_bfloat16* __restrict__ out_qkv,   // q base; k,v at +QKV_STRIDE
    float* __restrict__ out_f32)
{
    constexpr int K = Cn;
    constexpr int NSTEP = K / 64;             // 16
    __shared__ char smem[65536];               // [buf][A 16KB | B 16KB]

    const int m0 = blockIdx.x * 128;
    const int n0 = blockIdx.y * 128;

    const int tid = threadIdx.x;
    const int lane = tid & 63, wid = tid >> 6;
    const int wy = wid >> 1, wx = wid & 1;
    const int fr = lane & 15, g = lane >> 4;
    const int rxor = (fr & 7) << 4;

    floatx4 acc[4][4] = {};

    int srow[4], scol[4], doff[4];
#pragma unroll
    for (int i = 0; i < 4; ++i) {
        int byteoff = wid * 4096 + i * 1024 + lane * 16;
        int r = byteoff >> 7;
        int ch = (byteoff >> 4) & 7;
        srow[i] = r;
        scol[i] = (ch ^ (r & 7)) << 3;
        doff[i] = wid * 4096 + i * 1024;       // wave-uniform LDS offset
    }

    // prologue: stage K-tile 0 into buf 0, drain, barrier
#pragma unroll
    for (int i = 0; i < 4; ++i) {
        gl_lds16(&A[(size_t)(m0 + srow[i]) * K + scol[i]], smem + doff[i]);
        gl_lds16(&BT[(size_t)(n0 + srow[i]) * K + scol[i]], smem + 16384 + doff[i]);
    }
    asm volatile("s_waitcnt vmcnt(0)" ::: "memory");
    asm volatile("s_barrier" ::: "memory");

    int cur = 0;
    for (int t = 0; t < NSTEP; ++t) {
        // phase A: issue next K-tile's DMA into the other buffer
        if (t + 1 < NSTEP) {
            const int k0 = (t + 1) * 64;
            char* dst = smem + (cur ^ 1) * 32768;
#pragma unroll
            for (int i = 0; i < 4; ++i) {
                gl_lds16(&A[(size_t)(m0 + srow[i]) * K + k0 + scol[i]], dst + doff[i]);
                gl_lds16(&BT[(size_t)(n0 + srow[i]) * K + k0 + scol[i]], dst + 16384 + doff[i]);
            }
        }
        // phase B: compute current buffer
        const char* lA0 = smem + cur * 32768;
        const char* lB0 = lA0 + 16384;
#pragma unroll
        for (int kk = 0; kk < 2; ++kk) {
            short8 af[4], bf[4];
#pragma unroll
            for (int t4 = 0; t4 < 4; ++t4) {
                af[t4] = *(const short8*)(lA0 + (wy * 64 + t4 * 16 + fr) * 128 + ((kk * 64 + g * 16) ^ rxor));
                bf[t4] = *(const short8*)(lB0 + (wx * 64 + t4 * 16 + fr) * 128 + ((kk * 64 + g * 16) ^ rxor));
            }
            __builtin_amdgcn_s_setprio(1);
#pragma unroll
            for (int tm = 0; tm < 4; ++tm)
#pragma unroll
                for (int tn = 0; tn < 4; ++tn)
                    acc[tm][tn] = __builtin_amdgcn_mfma_f32_16x16x32_bf16(af[tm], bf[tn], acc[tm][tn], 0, 0, 0);
            __builtin_amdgcn_s_setprio(0);
        }
        // phase C: next tile landed + all waves done reading -> swap
        asm volatile("s_waitcnt vmcnt(0)" ::: "memory");
        asm volatile("s_barrier" ::: "memory");
        cur ^= 1;
    }

    for (int tm = 0; tm < 4; ++tm) {
        int rbase = m0 + wy * 64 + tm * 16 + g * 4;
        for (int tn = 0; tn < 4; ++tn) {
            int nc = n0 + wx * 64 + tn * 16 + fr;
            if (MODE == 0) {
                int w = nc >> 10, rem = nc & 1023, hh = rem >> 6, dd = rem & 63;
                if (w == 2) {
                    int b = rbase >> 11, t0 = rbase & 2047;
                    // permuted column position within the 32-block (quad-aligned t0)
                    int pos = (t0 & ~31) | (((t0 >> 2) & 3) << 3) | (((t0 >> 4) & 1) << 2);
                    ushort4 pk;
                    pk.x = bfbits(acc[tm][tn][0]);
                    pk.y = bfbits(acc[tm][tn][1]);
                    pk.z = bfbits(acc[tm][tn][2]);
                    pk.w = bfbits(acc[tm][tn][3]);
                    *(ushort4*)(&out_qkv[2 * QKV_STRIDE +
                        ((size_t)((b * Hn + hh) * DHn + dd)) * Tn + pos]) = pk;
                } else {
                    for (int r = 0; r < 4; ++r) {
                        int m = rbase + r;
                        int b = m >> 11, t = m & 2047;
                        out_qkv[(size_t)w * QKV_STRIDE + (((size_t)(b * Hn + hh) * Tn + t) << 6) + dd] =
                            __float2bfloat16(acc[tm][tn][r]);
                    }
                }
            } else {
                float bs = bias[nc];
                for (int r = 0; r < 4; ++r) {
                    int m = rbase + r;
                    out_f32[(size_t)m * Cn + nc] = acc[tm][tn][r] + bs;
                }
            }
        }
    }
}

// ---------------- causal flash attention v12 (R15-proven) ----------------
__global__ __launch_bounds__(256, 4) void attn_kernel(
    const __hip_bfloat16* __restrict__ q,
    const __hip_bfloat16* __restrict__ k,
    const __hip_bfloat16* __restrict__ vt,
    __hip_bfloat16* __restrict__ ao)
{
    __shared__ char smem[32768];   // K bufs [2][8KB] @0, V bufs [2][8KB] @16384

    const int id = blockIdx.x;               // 0..1023
    const int xcd = id & 7;
    const int rnk = id >> 3;                 // 0..127 within XCD stream
    const int tile = 15 - (rnk >> 3);        // longest-first (LPT)
    const int bh = xcd * 8 + (rnk & 7);      // XCD-clustered heads
    const int b = bh >> 4, h = bh & 15;
    const int tid = threadIdx.x, lane = tid & 63, wid = tid >> 6;
    const int fr = lane & 15, g = lane >> 4;
    const size_t base = (size_t)bh * Tn * DHn;
    const int rxor = (fr & 7) << 4;

    const int r0 = wid * 16 + (lane >> 3);
    const int c8 = ((lane & 7) ^ (r0 & 7)) * 8;
    const int ldk0 = wid * 2048;

    short8 ones;
#pragma unroll
    for (int z = 0; z < 8; ++z) ones[z] = (short)0x3F80;

    const int qb0 = tile * 128;
    const int q0 = qb0 + wid * 32;
    const int nkv = qb0 / 64 + 2;

    short8 aq[2][2];
#pragma unroll
    for (int rq = 0; rq < 2; ++rq)
#pragma unroll
        for (int kk = 0; kk < 2; ++kk)
            aq[rq][kk] = *(const short8*)(&q[base + (size_t)(q0 + rq * 16 + fr) * DHn + kk * 32 + g * 8]);

    floatx4 o[2][4] = {};
    floatx4 o5[2] = {};    // l-sum accumulators (ones-MFMA)

    // prologue: stage j=0 -> buf0
    {
        char* kd = smem + ldk0;
        char* vd = smem + 16384 + ldk0;
        gl_lds16(&k[base + (size_t)r0 * DHn + c8], kd);
        gl_lds16(&k[base + (size_t)(r0 + 8) * DHn + c8], kd + 1024);
        gl_lds16(&vt[base + (size_t)r0 * Tn + c8], vd);
        gl_lds16(&vt[base + (size_t)(r0 + 8) * Tn + c8], vd + 1024);
    }
    asm volatile("s_waitcnt vmcnt(0)" ::: "memory");
    __builtin_amdgcn_s_barrier();

    int cur = 0;
    for (int j = 0; j < nkv; ++j) {
        const int kv0 = j * 64;

        // issue j+1 -> buf cur^1 (closed by the previous step's barrier)
        if (j + 1 < nkv) {
            const int nv0 = kv0 + 64;
            char* kd = smem + (cur ^ 1) * 8192 + ldk0;
            char* vd = smem + 16384 + (cur ^ 1) * 8192 + ldk0;
            gl_lds16(&k[base + (size_t)(nv0 + r0) * DHn + c8], kd);
            gl_lds16(&k[base + (size_t)(nv0 + r0 + 8) * DHn + c8], kd + 1024);
            gl_lds16(&vt[base + (size_t)r0 * Tn + nv0 + c8], vd);
            gl_lds16(&vt[base + (size_t)(r0 + 8) * Tn + nv0 + c8], vd + 1024);
        }

        if (kv0 < q0 + 32) {
            const char* lkc = smem + cur * 8192;
            const char* lvc = smem + 16384 + cur * 8192;

            // ---- QK^T (swapped): s[rq][cg] row k = cg*16+g*4+r, col q = fr ----
            floatx4 s[2][4] = {};
            __builtin_amdgcn_s_setprio(1);
#pragma unroll
            for (int kk = 0; kk < 2; ++kk)
#pragma unroll
                for (int cg = 0; cg < 4; ++cg) {
                    short8 kf = *(const short8*)(lkc + (cg * 16 + fr) * 128 + ((g * 16 + kk * 64) ^ rxor));
                    s[0][cg] = __builtin_amdgcn_mfma_f32_16x16x32_bf16(kf, aq[0][kk], s[0][cg], 0, 0, 0);
                    s[1][cg] = __builtin_amdgcn_mfma_f32_16x16x32_bf16(kf, aq[1][kk], s[1][cg], 0, 0, 0);
                }
            __builtin_amdgcn_s_setprio(0);

            // ---- causal mask (diagonal region only) ----
            if (kv0 + 64 > q0) {
#pragma unroll
                for (int rq = 0; rq < 2; ++rq) {
                    int qg = q0 + rq * 16 + fr;
#pragma unroll
                    for (int cg = 0; cg < 4; ++cg) {
                        int kg = kv0 + cg * 16 + g * 4;
#pragma unroll
                        for (int r = 0; r < 4; ++r)
                            if (kg + r > qg) s[rq][cg][r] = -1e30f;
                    }
                }
            }

            // ---- fixed-reference softmax: p = exp2(s); pack via v_cvt_pk_bf16_f32 ----
            short8 pb[2][2];
#pragma unroll
            for (int rq = 0; rq < 2; ++rq) {
#pragma unroll
                for (int cg = 0; cg < 4; ++cg)
#pragma unroll
                    for (int r = 0; r < 4; ++r)
                        s[rq][cg][r] = __builtin_amdgcn_exp2f(s[rq][cg][r]);
#pragma unroll
                for (int kt = 0; kt < 2; ++kt) {
                    u32x4 wv;
                    wv[0] = cvtpk(s[rq][2 * kt][0],     s[rq][2 * kt][1]);
                    wv[1] = cvtpk(s[rq][2 * kt][2],     s[rq][2 * kt][3]);
                    wv[2] = cvtpk(s[rq][2 * kt + 1][0], s[rq][2 * kt + 1][1]);
                    wv[3] = cvtpk(s[rq][2 * kt + 1][2], s[rq][2 * kt + 1][3]);
                    pb[rq][kt] = __builtin_bit_cast(short8, wv);
                }
            }

            // ---- l via ones-MFMA + PV (contiguous b128 reads: V^T columns pre-permuted) ----
            __builtin_amdgcn_s_setprio(1);
#pragma unroll
            for (int rq = 0; rq < 2; ++rq)
#pragma unroll
                for (int kt = 0; kt < 2; ++kt)
                    o5[rq] = __builtin_amdgcn_mfma_f32_16x16x32_bf16(ones, pb[rq][kt], o5[rq], 0, 0, 0);
#pragma unroll
            for (int kt = 0; kt < 2; ++kt)
#pragma unroll
                for (int dg = 0; dg < 4; ++dg) {
                    const int vrow = (dg * 16 + fr) * 128;
                    short8 vf = *(const short8*)(lvc + vrow + ((kt * 64 + g * 16) ^ rxor));
                    o[0][dg] = __builtin_amdgcn_mfma_f32_16x16x32_bf16(vf, pb[0][kt], o[0][dg], 0, 0, 0);
                    o[1][dg] = __builtin_amdgcn_mfma_f32_16x16x32_bf16(vf, pb[1][kt], o[1][dg], 0, 0, 0);
                }
            __builtin_amdgcn_s_setprio(0);
        }

        asm volatile("s_waitcnt vmcnt(0)" ::: "memory");
        __builtin_amdgcn_s_barrier();
        cur ^= 1;
    }

    // ---- epilogue: normalize (l = o5 via MFMA rowsum), transpose, store ----
    char* myscr = smem + wid * 4096;   // per-wave 16x64 f32 region
    const int rr = lane >> 2, cc = lane & 3;
#pragma unroll
    for (int rq = 0; rq < 2; ++rq) {
        const float inv = 1.0f / o5[rq][0];
#pragma unroll
        for (int dg = 0; dg < 4; ++dg) {
            floatx4 wv = o[rq][dg] * inv;
            *(floatx4*)(myscr + fr * 256 + ((dg * 64 + g * 16) ^ rxor)) = wv;
        }
        asm volatile("s_waitcnt lgkmcnt(0)" ::: "memory");
        float4 f0 = *(const float4*)(myscr + rr * 256 + ((cc * 64 + 0) ^ ((rr & 7) << 4)));
        float4 f1 = *(const float4*)(myscr + rr * 256 + ((cc * 64 + 16) ^ ((rr & 7) << 4)));
        float4 f2 = *(const float4*)(myscr + rr * 256 + ((cc * 64 + 32) ^ ((rr & 7) << 4)));
        float4 f3 = *(const float4*)(myscr + rr * 256 + ((cc * 64 + 48) ^ ((rr & 7) << 4)));
        short8 pk0, pk1;
        pk0[0] = (short)bfbits(f0.x); pk0[1] = (short)bfbits(f0.y);
        pk0[2] = (short)bfbits(f0.z); pk0[3] = (short)bfbits(f0.w);
        pk0[4] = (short)bfbits(f1.x); pk0[5] = (short)bfbits(f1.y);
        pk0[6] = (short)bfbits(f1.z); pk0[7] = (short)bfbits(f1.w);
        pk1[0] = (short)bfbits(f2.x); pk1[1] = (short)bfbits(f2.y);
        pk1[2] = (short)bfbits(f2.z); pk1[3] = (short)bfbits(f2.w);
        pk1[4] = (short)bfbits(f3.x); pk1[5] = (short)bfbits(f3.y);
        pk1[6] = (short)bfbits(f3.z); pk1[7] = (short)bfbits(f3.w);
        size_t orow = ((size_t)(b * Tn + q0 + rq * 16 + rr)) * Cn + h * 64 + cc * 16;
        *(short8*)(&ao[orow]) = pk0;
        *(short8*)(&ao[orow + 8]) = pk1;
        asm volatile("s_waitcnt lgkmcnt(0)" ::: "memory");
    }
}

extern "C" void kernel_launch(void* const* d_in, const int* in_sizes, int n_in,
                              void* d_out, int out_size, void* d_ws, size_t ws_size,
                              hipStream_t stream) {
    const float* x  = (const float*)d_in[0];
    const float* Wq = (const float*)d_in[1];
    const float* Wk = (const float*)d_in[2];
    const float* Wv = (const float*)d_in[3];
    const float* Wo = (const float*)d_in[4];
    const float* bo = (const float*)d_in[5];
    float* out = (float*)d_out;

    char* ws = (char*)d_ws;
    __hip_bfloat16* xb  = (__hip_bfloat16*)(ws);                    // [8192][1024]        16 MB
    __hip_bfloat16* wT  = (__hip_bfloat16*)(ws + 16777216);         // [3][1024][1024]      6 MB
    __hip_bfloat16* woT = (__hip_bfloat16*)(ws + 23068672);         // [1024][1024]         2 MB
    __hip_bfloat16* qb  = (__hip_bfloat16*)(ws + 25165824);         // q,k,v each 16 MB
    __hip_bfloat16* ao  = (__hip_bfloat16*)(ws + 75497472);         // [8192][1024]        16 MB

    // x -> bf16 (8 floats/thread)
    conv_kernel<<<(Mtot * Cn / 8 + 255) / 256, 256, 0, stream>>>(
        (const float4*)x, (ushort4*)xb, Mtot * Cn / 8);
    // fused Wq/Wk/Wv transpose+convert (Wq carries 0.125*log2e)
    tconv3_kernel<<<dim3(2, 32, 48), dim3(32, 8), 0, stream>>>(Wq, Wk, Wv, wT);
    // Wo transpose+convert
    tconv_kernel<<<dim3(32, 32, 1), dim3(32, 8), 0, stream>>>(Wo, woT, Cn, Cn);

    // QKV projection: M=8192, N=3072 (V stored transposed, columns permuted)
    gemm_kernel<0><<<dim3(Mtot / 128, 3072 / 128), 256, 0, stream>>>(
        xb, wT, nullptr, qb, nullptr);

    // causal flash attention: 1024 single-tile blocks, LPT per XCD, 4 blocks/CU
    attn_kernel<<<dim3(1024), 256, 0, stream>>>(
        qb, qb + QKV_STRIDE, qb + 2 * QKV_STRIDE, ao);

    // output projection: M=8192, N=1024, +bias, f32 out
    gemm_kernel<1><<<dim3(Mtot / 128, Cn / 128), 256, 0, stream>>>(
        ao, woT, bo, nullptr, out);
}